// Round 6
// baseline (165.736 us; speedup 1.0000x reference)
//
#include <hip/hip_runtime.h>
#include <stdint.h>
#include <math.h>

#define NN 8192
#define DD 128
#define NB 64                    // 8192/128 tiles per dim
#define NBLK (NB * (NB + 1) / 2) // 2080 upper-triangular tile blocks
#define NC 32                    // classes
#define NPB 256                  // prep blocks (= class partial blocks)
#define RPB 32                   // rows per prep block
#define TOTBLK (NBLK + NC)       // fused loss grid

typedef __attribute__((ext_vector_type(4))) float f32x4;

// fp8 e4m3 fragment-major layout (for mfma_f32_16x16x32_fp8_fp8):
// panel = row>>4; byte(row,k) = panel*2048 + (k>>5)*512 + ((k>>3)&3)*128 + (row&15)*8 + (k&7)
// -> wave-load for (panel, ks): lane l reads 8B at panel*2048 + ks*512 + (l>>4)*128 + (l&15)*8
//    (contiguous 512B per wave, fully coalesced; lane holds 8 consecutive k for its row)

__device__ __forceinline__ uint32_t pk4_fp8(float f0, float f1, float f2, float f3) {
    int d = __builtin_amdgcn_cvt_pk_fp8_f32(f0, f1, 0, false);   // bytes 0,1
    d = __builtin_amdgcn_cvt_pk_fp8_f32(f2, f3, d, true);        // bytes 2,3
    return (uint32_t)d;
}

// prep: 256 blocks x 32 rows. fp8 cast into a8 (= -2y) / b8 (= y) frag-major +
// exact fp32 row norms + per-block per-class partial sums (2 LDS copies,
// atomic-free: group g x column col exclusively owns cls[g][*][col]).
__global__ __launch_bounds__(256) void prep_kernel(const float* __restrict__ ys,
                                                   const int* __restrict__ lab,
                                                   uint32_t* __restrict__ a8,
                                                   uint32_t* __restrict__ b8,
                                                   float* __restrict__ sq,
                                                   float* __restrict__ clspart,
                                                   float* __restrict__ negacc,
                                                   int* __restrict__ ticket) {
    int b = blockIdx.x, t = threadIdx.x;
    __shared__ float cls[2][NC][DD];   // 32 KB
    __shared__ int slab[RPB];

#pragma unroll
    for (int i = 0; i < 8; ++i) ((float4*)cls)[i * 256 + t] = make_float4(0.f, 0.f, 0.f, 0.f);
    if (t < RPB) slab[t] = lab[b * RPB + t];

#pragma unroll
    for (int u = 0; u < 2; ++u) {
        int rloc = (t >> 4) + u * 16;   // 0..31
        int c8 = t & 15;                // 8-float chunk within row (k = c8*8)
        int row = b * RPB + rloc;
        const float* base = ys + (size_t)row * DD + c8 * 8;
        float4 v0 = *(const float4*)base;
        float4 v1 = *(const float4*)(base + 4);
        uint2 outB = make_uint2(pk4_fp8(v0.x, v0.y, v0.z, v0.w),
                                pk4_fp8(v1.x, v1.y, v1.z, v1.w));
        uint2 outA = make_uint2(pk4_fp8(-2.f * v0.x, -2.f * v0.y, -2.f * v0.z, -2.f * v0.w),
                                pk4_fp8(-2.f * v1.x, -2.f * v1.y, -2.f * v1.z, -2.f * v1.w));
        // panel = b*2+u; ks = c8>>2; kgrp = c8&3; row-in-panel = rloc&15
        size_t off = (size_t)(b * 2 + u) * 2048 + (c8 >> 2) * 512 + (c8 & 3) * 128 + (rloc & 15) * 8;
        *(uint2*)((char*)b8 + off) = outB;
        *(uint2*)((char*)a8 + off) = outA;
        float s = v0.x * v0.x + v0.y * v0.y + v0.z * v0.z + v0.w * v0.w
                + v1.x * v1.x + v1.y * v1.y + v1.z * v1.z + v1.w * v1.w;
        s += __shfl_xor(s, 1); s += __shfl_xor(s, 2);
        s += __shfl_xor(s, 4); s += __shfl_xor(s, 8);
        if (c8 == 0) sq[row] = s;
    }
    __syncthreads();

    // Atomic-free class accumulation: group g handles 16 rows into its own copy.
    {
        int g = t >> 7, col = t & 127;
#pragma unroll
        for (int rr = 0; rr < 16; ++rr) {
            int rloc = g * 16 + rr;
            cls[g][slab[rloc]][col] += ys[(size_t)(b * RPB + rloc) * DD + col];
        }
    }
    __syncthreads();
#pragma unroll
    for (int i = 0; i < 4; ++i) {
        float4 a = ((const float4*)cls[0])[i * 256 + t];
        float4 c = ((const float4*)cls[1])[i * 256 + t];
        ((float4*)(clspart + (size_t)b * NC * DD))[i * 256 + t] =
            make_float4(a.x + c.x, a.y + c.y, a.z + c.z, a.w + c.w);
    }
    if (b == 0 && t == 0) { *negacc = 0.f; *ticket = 0; }
}

// Fused loss: blocks 0..31 = classred (pos_c = n_c*ssq_c - ||S_c||^2);
// blocks 32..2111 = LDS-free fp8 tile GEMM (acc C-init = sq_i+sq_j, A=-2y
// => acc ends as d2). Last block (ticket) finalizes the scalar output.
__global__ __launch_bounds__(256) void loss_kernel(const uint32_t* __restrict__ a8,
                                                   const uint32_t* __restrict__ b8,
                                                   const float* __restrict__ sq,
                                                   const int* __restrict__ lab,
                                                   const float* __restrict__ clspart,
                                                   float* __restrict__ posval,
                                                   float* __restrict__ negacc,
                                                   int* __restrict__ ticket,
                                                   float* __restrict__ out) {
    int p = blockIdx.x, t = threadIdx.x;
    __shared__ int lastf;

    if (p < NC) {
        // ---- classred for class p ----
        __shared__ float sp[2][DD];
        __shared__ float redc[4], reds[4], red2[2];
        int col = t & 127, qr = t >> 7;
        float S = 0.f;
#pragma unroll 8
        for (int pb = qr; pb < NPB; pb += 2) S += clspart[(size_t)pb * NC * DD + p * DD + col];
        sp[qr][col] = S;

        float cnt = 0.f, ssq = 0.f;
#pragma unroll
        for (int rr = t; rr < NN; rr += 256) {
            if (lab[rr] == p) { cnt += 1.f; ssq += sq[rr]; }
        }
#pragma unroll
        for (int off = 32; off >= 1; off >>= 1) {
            cnt += __shfl_down(cnt, off);
            ssq += __shfl_down(ssq, off);
        }
        if ((t & 63) == 0) { redc[t >> 6] = cnt; reds[t >> 6] = ssq; }
        __syncthreads();

        float s2 = 0.f;
        if (t < DD) { float Sc = sp[0][t] + sp[1][t]; s2 = Sc * Sc; }
#pragma unroll
        for (int off = 32; off >= 1; off >>= 1) s2 += __shfl_down(s2, off);
        if (t < 128 && (t & 63) == 0) red2[t >> 6] = s2;
        __syncthreads();
        if (t == 0) {
            float c = redc[0] + redc[1] + redc[2] + redc[3];
            float s = reds[0] + reds[1] + reds[2] + reds[3];
            posval[p] = c * s - (red2[0] + red2[1]);
        }
    } else {
        // ---- tile GEMM for pt ----
        int pt = p - NC;
        int q = (NBLK - 1) - pt;
        int r = (int)((sqrtf(8.0f * (float)q + 1.0f) - 1.0f) * 0.5f);
        while (r * (r + 1) / 2 > q) --r;
        while ((r + 1) * (r + 2) / 2 <= q) ++r;
        int bi = (NB - 1) - r;
        int bj = (NB - 1) - (q - r * (r + 1) / 2);
        int i0 = bi * 128, j0 = bj * 128;

        int wave = t >> 6, lane = t & 63;
        int wm = wave >> 1, wn = wave & 1;
        int lr = lane & 15, lg = lane >> 4;

        float sqa[4][4], sqb[4];
#pragma unroll
        for (int m = 0; m < 4; ++m)
#pragma unroll
            for (int qq = 0; qq < 4; ++qq) sqa[m][qq] = sq[i0 + wm * 64 + m * 16 + lg * 4 + qq];
#pragma unroll
        for (int n = 0; n < 4; ++n) sqb[n] = sq[j0 + wn * 64 + n * 16 + lr];

        f32x4 acc[4][4];
#pragma unroll
        for (int m = 0; m < 4; ++m)
#pragma unroll
            for (int n = 0; n < 4; ++n) {
                f32x4 a;
#pragma unroll
                for (int qq = 0; qq < 4; ++qq) a[qq] = sqa[m][qq] + sqb[n];
                acc[m][n] = a;
            }

        const char* pa = (const char*)a8 + ((size_t)(i0 >> 4) + wm * 4) * 2048 + lg * 128 + lr * 8;
        const char* pbp = (const char*)b8 + ((size_t)(j0 >> 4) + wn * 4) * 2048 + lg * 128 + lr * 8;

#pragma unroll
        for (int ks = 0; ks < 4; ++ks) {
            long af[4], bf[4];
#pragma unroll
            for (int m = 0; m < 4; ++m) af[m] = *(const long*)(pa + m * 2048 + ks * 512);
#pragma unroll
            for (int n = 0; n < 4; ++n) bf[n] = *(const long*)(pbp + n * 2048 + ks * 512);
#pragma unroll
            for (int m = 0; m < 4; ++m)
#pragma unroll
                for (int n = 0; n < 4; ++n)
                    acc[m][n] = __builtin_amdgcn_mfma_f32_16x16x32_fp8_fp8(af[m], bf[n], acc[m][n], 0, 0, 0);
        }

        // acc[m][n][q] == d2(i,j) (fp8-accurate, err ~ +-2; threshold widened to 4).
        float mn = acc[0][0][0];
#pragma unroll
        for (int m = 0; m < 4; ++m)
#pragma unroll
            for (int n = 0; n < 4; ++n)
#pragma unroll
                for (int qq = 0; qq < 4; ++qq) mn = fminf(mn, acc[m][n][qq]);

        if (__any(mn < 4.0f)) {
            float ns = 0.f;
#pragma unroll
            for (int m = 0; m < 4; ++m)
#pragma unroll
                for (int n = 0; n < 4; ++n)
#pragma unroll
                    for (int qq = 0; qq < 4; ++qq) {
                        float d2 = acc[m][n][qq];
                        if (d2 < 1.0f) {
                            int i = i0 + wm * 64 + m * 16 + lg * 4 + qq;
                            int j = j0 + wn * 64 + n * 16 + lr;
                            if (i < j && lab[i] != lab[j]) {
                                float e = 1.0f - sqrtf(fmaxf(d2, 0.f));
                                ns += e * e;
                            }
                        }
                    }
            if (ns != 0.f) atomicAdd(negacc, ns);
        }
    }

    // ---- ticket: last block finalizes ----
    __threadfence();
    __syncthreads();
    if (t == 0) lastf = (atomicAdd(ticket, 1) == TOTBLK - 1) ? 1 : 0;
    __syncthreads();
    if (lastf) {
        __threadfence();
        if (t < 64) {
            float s = (t < NC) ? posval[t] : 0.f;
#pragma unroll
            for (int off = 32; off >= 1; off >>= 1) s += __shfl_down(s, off);
            if (t == 0) out[0] = (s + *negacc) * (2.0f / ((float)NN * (float)(NN - 1)));
        }
    }
}

extern "C" void kernel_launch(void* const* d_in, const int* in_sizes, int n_in,
                              void* d_out, int out_size, void* d_ws, size_t ws_size,
                              hipStream_t stream) {
    const float* ys = (const float*)d_in[0];
    const int* lab = (const int*)d_in[1];
    float* out = (float*)d_out;

    char* w = (char*)d_ws;
    uint32_t* a8    = (uint32_t*)(w);                 // 1 MB (-2y fp8, frag-major)
    uint32_t* b8    = (uint32_t*)(w + 1048576);       // 1 MB (y fp8)
    float* sq       = (float*)(w + 2097152);          // 32 KB
    float* clspart  = (float*)(w + 2129920);          // 4 MB
    float* posval   = (float*)(w + 6324224);          // 128 B
    float* negacc   = (float*)(w + 6324352);          // 4 B
    int* ticket     = (int*)(w + 6324356);            // 4 B

    prep_kernel<<<NPB, 256, 0, stream>>>(ys, lab, a8, b8, sq, clspart, negacc, ticket);
    loss_kernel<<<TOTBLK, 256, 0, stream>>>(a8, b8, sq, lab, clspart, posval, negacc, ticket, out);
}

// Round 7
// 32.911 us; speedup vs baseline: 5.0359x; 5.0359x over previous
//
#include <hip/hip_runtime.h>
#include <stdint.h>
#include <math.h>

#define NN 8192
#define DD 128
#define NB 64                    // 8192/128 tiles per dim
#define NBLK (NB * (NB + 1) / 2) // 2080 upper-triangular tile blocks
#define NC 32                    // classes
#define NPB 256                  // prep blocks (= class partial blocks)
#define RPB 32                   // rows per prep block
#define TOTBLK (NBLK + NC)       // fused loss grid

typedef __attribute__((ext_vector_type(4))) float f32x4;

// fp8 e4m3 fragment-major layout (for mfma_f32_16x16x32_fp8_fp8):
// panel = row>>4; byte(row,k) = panel*2048 + (k>>5)*512 + ((k>>3)&3)*128 + (row&15)*8 + (k&7)
// -> wave-load for (panel, ks): lane l reads 8B at panel*2048 + ks*512 + (l>>4)*128 + (l&15)*8
//    (contiguous 512B per wave, fully coalesced; lane holds 8 consecutive k of its row)

__device__ __forceinline__ uint32_t pk4_fp8(float f0, float f1, float f2, float f3) {
    int d = __builtin_amdgcn_cvt_pk_fp8_f32(f0, f1, 0, false);   // bytes 0,1
    d = __builtin_amdgcn_cvt_pk_fp8_f32(f2, f3, d, true);        // bytes 2,3
    return (uint32_t)d;
}

// prep: 256 blocks x 32 rows. fp8 cast into a8 (= -2y) / b8 (= y) frag-major +
// exact fp32 row norms + per-block per-class partial sums (2 LDS copies,
// atomic-free: group g x column col exclusively owns cls[g][*][col]).
__global__ __launch_bounds__(256) void prep_kernel(const float* __restrict__ ys,
                                                   const int* __restrict__ lab,
                                                   uint32_t* __restrict__ a8,
                                                   uint32_t* __restrict__ b8,
                                                   float* __restrict__ sq,
                                                   float* __restrict__ clspart,
                                                   float* __restrict__ negacc) {
    int b = blockIdx.x, t = threadIdx.x;
    __shared__ float cls[2][NC][DD];   // 32 KB
    __shared__ int slab[RPB];

#pragma unroll
    for (int i = 0; i < 8; ++i) ((float4*)cls)[i * 256 + t] = make_float4(0.f, 0.f, 0.f, 0.f);
    if (t < RPB) slab[t] = lab[b * RPB + t];

#pragma unroll
    for (int u = 0; u < 2; ++u) {
        int rloc = (t >> 4) + u * 16;   // 0..31
        int c8 = t & 15;                // 8-float chunk within row (k = c8*8)
        int row = b * RPB + rloc;
        const float* base = ys + (size_t)row * DD + c8 * 8;
        float4 v0 = *(const float4*)base;
        float4 v1 = *(const float4*)(base + 4);
        uint2 outB = make_uint2(pk4_fp8(v0.x, v0.y, v0.z, v0.w),
                                pk4_fp8(v1.x, v1.y, v1.z, v1.w));
        uint2 outA = make_uint2(pk4_fp8(-2.f * v0.x, -2.f * v0.y, -2.f * v0.z, -2.f * v0.w),
                                pk4_fp8(-2.f * v1.x, -2.f * v1.y, -2.f * v1.z, -2.f * v1.w));
        size_t off = (size_t)(b * 2 + u) * 2048 + (c8 >> 2) * 512 + (c8 & 3) * 128 + (rloc & 15) * 8;
        *(uint2*)((char*)b8 + off) = outB;
        *(uint2*)((char*)a8 + off) = outA;
        float s = v0.x * v0.x + v0.y * v0.y + v0.z * v0.z + v0.w * v0.w
                + v1.x * v1.x + v1.y * v1.y + v1.z * v1.z + v1.w * v1.w;
        s += __shfl_xor(s, 1); s += __shfl_xor(s, 2);
        s += __shfl_xor(s, 4); s += __shfl_xor(s, 8);
        if (c8 == 0) sq[row] = s;
    }
    __syncthreads();

    // Atomic-free class accumulation: group g handles 16 rows into its own copy.
    {
        int g = t >> 7, col = t & 127;
#pragma unroll
        for (int rr = 0; rr < 16; ++rr) {
            int rloc = g * 16 + rr;
            cls[g][slab[rloc]][col] += ys[(size_t)(b * RPB + rloc) * DD + col];
        }
    }
    __syncthreads();
#pragma unroll
    for (int i = 0; i < 4; ++i) {
        float4 a = ((const float4*)cls[0])[i * 256 + t];
        float4 c = ((const float4*)cls[1])[i * 256 + t];
        ((float4*)(clspart + (size_t)b * NC * DD))[i * 256 + t] =
            make_float4(a.x + c.x, a.y + c.y, a.z + c.z, a.w + c.w);
    }
    if (b == 0 && t == 0) *negacc = 0.f;
}

// Fused loss: blocks 0..31 = classred (pos_c = n_c*ssq_c - ||S_c||^2);
// blocks 32..2111 = LDS-free fp8 tile GEMM (acc C-init = sq_i+sq_j, A=-2y
// => acc ends as d2). No fences, no tickets — finalize is a separate kernel.
__global__ __launch_bounds__(256) void loss_kernel(const uint32_t* __restrict__ a8,
                                                   const uint32_t* __restrict__ b8,
                                                   const float* __restrict__ sq,
                                                   const int* __restrict__ lab,
                                                   const float* __restrict__ clspart,
                                                   float* __restrict__ posval,
                                                   float* __restrict__ negacc) {
    int p = blockIdx.x, t = threadIdx.x;

    if (p < NC) {
        // ---- classred for class p: 4 independent accumulators for ILP ----
        __shared__ float sp[2][DD];
        __shared__ float redc[4], reds[4], red2[2];
        int col = t & 127, half = t >> 7;
        float S0 = 0.f, S1 = 0.f, S2 = 0.f, S3 = 0.f;
        const float* cp = clspart + (size_t)half * 128 * NC * DD + p * DD + col;
#pragma unroll 8
        for (int pb = 0; pb < 128; pb += 4) {
            S0 += cp[(size_t)(pb + 0) * NC * DD];
            S1 += cp[(size_t)(pb + 1) * NC * DD];
            S2 += cp[(size_t)(pb + 2) * NC * DD];
            S3 += cp[(size_t)(pb + 3) * NC * DD];
        }
        sp[half][col] = (S0 + S1) + (S2 + S3);

        float cnt = 0.f, ssq = 0.f;
        for (int rr = t; rr < NN; rr += 256) {
            if (lab[rr] == p) { cnt += 1.f; ssq += sq[rr]; }
        }
#pragma unroll
        for (int off = 32; off >= 1; off >>= 1) {
            cnt += __shfl_down(cnt, off);
            ssq += __shfl_down(ssq, off);
        }
        if ((t & 63) == 0) { redc[t >> 6] = cnt; reds[t >> 6] = ssq; }
        __syncthreads();

        float s2 = 0.f;
        if (t < DD) { float Sc = sp[0][t] + sp[1][t]; s2 = Sc * Sc; }
#pragma unroll
        for (int off = 32; off >= 1; off >>= 1) s2 += __shfl_down(s2, off);
        if (t < 128 && (t & 63) == 0) red2[t >> 6] = s2;
        __syncthreads();
        if (t == 0) {
            float c = redc[0] + redc[1] + redc[2] + redc[3];
            float s = reds[0] + reds[1] + reds[2] + reds[3];
            posval[p] = c * s - (red2[0] + red2[1]);
        }
    } else {
        // ---- tile GEMM ----
        int pt = p - NC;
        int q = (NBLK - 1) - pt;
        int r = (int)((sqrtf(8.0f * (float)q + 1.0f) - 1.0f) * 0.5f);
        while (r * (r + 1) / 2 > q) --r;
        while ((r + 1) * (r + 2) / 2 <= q) ++r;
        int bi = (NB - 1) - r;
        int bj = (NB - 1) - (q - r * (r + 1) / 2);
        int i0 = bi * 128, j0 = bj * 128;

        int wave = t >> 6, lane = t & 63;
        int wm = wave >> 1, wn = wave & 1;
        int lr = lane & 15, lg = lane >> 4;

        float sqa[4][4], sqb[4];
#pragma unroll
        for (int m = 0; m < 4; ++m)
#pragma unroll
            for (int qq = 0; qq < 4; ++qq) sqa[m][qq] = sq[i0 + wm * 64 + m * 16 + lg * 4 + qq];
#pragma unroll
        for (int n = 0; n < 4; ++n) sqb[n] = sq[j0 + wn * 64 + n * 16 + lr];

        f32x4 acc[4][4];
#pragma unroll
        for (int m = 0; m < 4; ++m)
#pragma unroll
            for (int n = 0; n < 4; ++n) {
                f32x4 a;
#pragma unroll
                for (int qq = 0; qq < 4; ++qq) a[qq] = sqa[m][qq] + sqb[n];
                acc[m][n] = a;
            }

        const char* pa = (const char*)a8 + ((size_t)(i0 >> 4) + wm * 4) * 2048 + lg * 128 + lr * 8;
        const char* pbp = (const char*)b8 + ((size_t)(j0 >> 4) + wn * 4) * 2048 + lg * 128 + lr * 8;

#pragma unroll
        for (int ks = 0; ks < 4; ++ks) {
            long af[4], bf[4];
#pragma unroll
            for (int m = 0; m < 4; ++m) af[m] = *(const long*)(pa + m * 2048 + ks * 512);
#pragma unroll
            for (int n = 0; n < 4; ++n) bf[n] = *(const long*)(pbp + n * 2048 + ks * 512);
#pragma unroll
            for (int m = 0; m < 4; ++m)
#pragma unroll
                for (int n = 0; n < 4; ++n)
                    acc[m][n] = __builtin_amdgcn_mfma_f32_16x16x32_fp8_fp8(af[m], bf[n], acc[m][n], 0, 0, 0);
        }

        // acc == d2(i,j) (fp8 err ~ +-3 vs d2 ~ 256; detect threshold widened to 4).
        float mn = acc[0][0][0];
#pragma unroll
        for (int m = 0; m < 4; ++m)
#pragma unroll
            for (int n = 0; n < 4; ++n)
#pragma unroll
                for (int qq = 0; qq < 4; ++qq) mn = fminf(mn, acc[m][n][qq]);

        if (__any(mn < 4.0f)) {
            float ns = 0.f;
#pragma unroll
            for (int m = 0; m < 4; ++m)
#pragma unroll
                for (int n = 0; n < 4; ++n)
#pragma unroll
                    for (int qq = 0; qq < 4; ++qq) {
                        float d2 = acc[m][n][qq];
                        if (d2 < 1.0f) {
                            int i = i0 + wm * 64 + m * 16 + lg * 4 + qq;
                            int j = j0 + wn * 64 + n * 16 + lr;
                            if (i < j && lab[i] != lab[j]) {
                                float e = 1.0f - sqrtf(fmaxf(d2, 0.f));
                                ns += e * e;
                            }
                        }
                    }
            if (ns != 0.f) atomicAdd(negacc, ns);
        }
    }
}

__global__ __launch_bounds__(64) void finalize_kernel(const float* __restrict__ posval,
                                                      const float* __restrict__ negacc,
                                                      float* __restrict__ out) {
    int t = threadIdx.x;
    float s = (t < NC) ? posval[t] : 0.f;
#pragma unroll
    for (int off = 32; off >= 1; off >>= 1) s += __shfl_down(s, off);
    if (t == 0) out[0] = (s + negacc[0]) * (2.0f / ((float)NN * (float)(NN - 1)));
}

extern "C" void kernel_launch(void* const* d_in, const int* in_sizes, int n_in,
                              void* d_out, int out_size, void* d_ws, size_t ws_size,
                              hipStream_t stream) {
    const float* ys = (const float*)d_in[0];
    const int* lab = (const int*)d_in[1];
    float* out = (float*)d_out;

    char* w = (char*)d_ws;
    uint32_t* a8    = (uint32_t*)(w);                 // 1 MB (-2y fp8, frag-major)
    uint32_t* b8    = (uint32_t*)(w + 1048576);       // 1 MB (y fp8)
    float* sq       = (float*)(w + 2097152);          // 32 KB
    float* clspart  = (float*)(w + 2129920);          // 4 MB
    float* posval   = (float*)(w + 6324224);          // 128 B
    float* negacc   = (float*)(w + 6324352);          // 4 B

    prep_kernel<<<NPB, 256, 0, stream>>>(ys, lab, a8, b8, sq, clspart, negacc);
    loss_kernel<<<TOTBLK, 256, 0, stream>>>(a8, b8, sq, lab, clspart, posval, negacc);
    finalize_kernel<<<1, 64, 0, stream>>>(posval, negacc, out);
}

// Round 8
// 32.199 us; speedup vs baseline: 5.1472x; 1.0221x over previous
//
#include <hip/hip_runtime.h>
#include <stdint.h>
#include <math.h>

#define NN 8192
#define DD 128
#define NB 64                    // 8192/128 tiles per dim
#define NBLK (NB * (NB + 1) / 2) // 2080 upper-triangular tile blocks
#define NC 32                    // classes
#define NPB 256                  // prep blocks (= class partial blocks)
#define RPB 32                   // rows per prep block
#define TOTBLK (NBLK + NC)       // fused loss grid
#define SCALE (2.0f / ((float)NN * (float)(NN - 1)))

typedef __attribute__((ext_vector_type(4))) float f32x4;

// fp8 e4m3 fragment-major layout (for mfma_f32_16x16x32_fp8_fp8):
// panel = row>>4; byte(row,k) = panel*2048 + (k>>5)*512 + ((k>>3)&3)*128 + (row&15)*8 + (k&7)
// -> wave-load for (panel, ks): lane l reads 8B at panel*2048 + ks*512 + (l>>4)*128 + (l&15)*8

__device__ __forceinline__ uint32_t pk4_fp8(float f0, float f1, float f2, float f3) {
    int d = __builtin_amdgcn_cvt_pk_fp8_f32(f0, f1, 0, false);   // bytes 0,1
    d = __builtin_amdgcn_cvt_pk_fp8_f32(f2, f3, d, true);        // bytes 2,3
    return (uint32_t)d;
}

// prep: 256 blocks x 32 rows. fp8 cast into a8 (= -2y) / b8 (= y) frag-major +
// exact fp32 row norms + per-block per-class partial sums (4 LDS copies,
// atomic-free: group g owns rows g*8..g*8+7; thread owns 2 columns).
// Also zeroes out[0] (loss kernel atomicAdds into it).
__global__ __launch_bounds__(256) void prep_kernel(const float* __restrict__ ys,
                                                   const int* __restrict__ lab,
                                                   uint32_t* __restrict__ a8,
                                                   uint32_t* __restrict__ b8,
                                                   float* __restrict__ sq,
                                                   float* __restrict__ clspart,
                                                   float* __restrict__ out) {
    int b = blockIdx.x, t = threadIdx.x;
    __shared__ float cls[4][NC][DD];   // 64 KB
    __shared__ int slab[RPB];

#pragma unroll
    for (int i = 0; i < 16; ++i) ((float4*)cls)[i * 256 + t] = make_float4(0.f, 0.f, 0.f, 0.f);
    if (t < RPB) slab[t] = lab[b * RPB + t];

#pragma unroll
    for (int u = 0; u < 2; ++u) {
        int rloc = (t >> 4) + u * 16;   // 0..31
        int c8 = t & 15;                // 8-float chunk within row (k = c8*8)
        int row = b * RPB + rloc;
        const float* base = ys + (size_t)row * DD + c8 * 8;
        float4 v0 = *(const float4*)base;
        float4 v1 = *(const float4*)(base + 4);
        uint2 outB = make_uint2(pk4_fp8(v0.x, v0.y, v0.z, v0.w),
                                pk4_fp8(v1.x, v1.y, v1.z, v1.w));
        uint2 outA = make_uint2(pk4_fp8(-2.f * v0.x, -2.f * v0.y, -2.f * v0.z, -2.f * v0.w),
                                pk4_fp8(-2.f * v1.x, -2.f * v1.y, -2.f * v1.z, -2.f * v1.w));
        size_t off = (size_t)(b * 2 + u) * 2048 + (c8 >> 2) * 512 + (c8 & 3) * 128 + (rloc & 15) * 8;
        *(uint2*)((char*)b8 + off) = outB;
        *(uint2*)((char*)a8 + off) = outA;
        float s = v0.x * v0.x + v0.y * v0.y + v0.z * v0.z + v0.w * v0.w
                + v1.x * v1.x + v1.y * v1.y + v1.z * v1.z + v1.w * v1.w;
        s += __shfl_xor(s, 1); s += __shfl_xor(s, 2);
        s += __shfl_xor(s, 4); s += __shfl_xor(s, 8);
        if (c8 == 0) sq[row] = s;
    }
    __syncthreads();

    // Atomic-free class accumulation: group g (of 4) handles 8 rows into its
    // own LDS copy; thread exclusively owns 2 columns. Chain length 8, 2-way ILP.
    {
        int g = t >> 6, col0 = (t & 63) * 2;
#pragma unroll
        for (int rr = 0; rr < 8; ++rr) {
            int rloc = g * 8 + rr;
            float2 v = *(const float2*)(ys + (size_t)(b * RPB + rloc) * DD + col0);
            int lb = slab[rloc];
            cls[g][lb][col0]     += v.x;
            cls[g][lb][col0 + 1] += v.y;
        }
    }
    __syncthreads();
#pragma unroll
    for (int i = 0; i < 4; ++i) {
        int idx = i * 256 + t;   // float4 index into [NC][DD] (1024 total)
        float4 s0 = ((const float4*)cls[0])[idx];
        float4 s1 = ((const float4*)cls[1])[idx];
        float4 s2 = ((const float4*)cls[2])[idx];
        float4 s3 = ((const float4*)cls[3])[idx];
        ((float4*)(clspart + (size_t)b * NC * DD))[idx] =
            make_float4((s0.x + s1.x) + (s2.x + s3.x), (s0.y + s1.y) + (s2.y + s3.y),
                        (s0.z + s1.z) + (s2.z + s3.z), (s0.w + s1.w) + (s2.w + s3.w));
    }
    if (b == 0 && t == 0) out[0] = 0.f;
}

// Fused loss: blocks 0..31 = classred -> atomicAdd(out, pos_c*SCALE);
// blocks 32..2111 = LDS-free fp8 tile GEMM. acc starts at 0 (no pre-MFMA
// loads); epilogue uses a conservative bound (min acc + min sq_i + min sq_j)
// to gate a never-taken slow path that re-verifies candidates EXACTLY from ys.
__global__ __launch_bounds__(256) void loss_kernel(const uint32_t* __restrict__ a8,
                                                   const uint32_t* __restrict__ b8,
                                                   const float* __restrict__ sq,
                                                   const int* __restrict__ lab,
                                                   const float* __restrict__ clspart,
                                                   const float* __restrict__ ys,
                                                   float* __restrict__ out) {
    int p = blockIdx.x, t = threadIdx.x;

    if (p < NC) {
        // ---- classred for class p: pos_c = n_c*ssq_c - ||S_c||^2 ----
        __shared__ float sp[2][DD];
        __shared__ float redc[4], reds[4], red2[2];
        int col = t & 127, half = t >> 7;
        float S0 = 0.f, S1 = 0.f, S2 = 0.f, S3 = 0.f;
        const float* cp = clspart + (size_t)half * 128 * NC * DD + p * DD + col;
#pragma unroll 8
        for (int pb = 0; pb < 128; pb += 4) {
            S0 += cp[(size_t)(pb + 0) * NC * DD];
            S1 += cp[(size_t)(pb + 1) * NC * DD];
            S2 += cp[(size_t)(pb + 2) * NC * DD];
            S3 += cp[(size_t)(pb + 3) * NC * DD];
        }
        sp[half][col] = (S0 + S1) + (S2 + S3);

        float cnt = 0.f, ssq = 0.f;
        for (int rr = t; rr < NN; rr += 256) {
            if (lab[rr] == p) { cnt += 1.f; ssq += sq[rr]; }
        }
#pragma unroll
        for (int off = 32; off >= 1; off >>= 1) {
            cnt += __shfl_down(cnt, off);
            ssq += __shfl_down(ssq, off);
        }
        if ((t & 63) == 0) { redc[t >> 6] = cnt; reds[t >> 6] = ssq; }
        __syncthreads();

        float s2 = 0.f;
        if (t < DD) { float Sc = sp[0][t] + sp[1][t]; s2 = Sc * Sc; }
#pragma unroll
        for (int off = 32; off >= 1; off >>= 1) s2 += __shfl_down(s2, off);
        if (t < 128 && (t & 63) == 0) red2[t >> 6] = s2;
        __syncthreads();
        if (t == 0) {
            float c = redc[0] + redc[1] + redc[2] + redc[3];
            float s = reds[0] + reds[1] + reds[2] + reds[3];
            atomicAdd(out, (c * s - (red2[0] + red2[1])) * SCALE);
        }
        return;
    }

    // ---- tile GEMM ----
    int pt = p - NC;
    int q = (NBLK - 1) - pt;
    int r = (int)((sqrtf(8.0f * (float)q + 1.0f) - 1.0f) * 0.5f);
    while (r * (r + 1) / 2 > q) --r;
    while ((r + 1) * (r + 2) / 2 <= q) ++r;
    int bi = (NB - 1) - r;
    int bj = (NB - 1) - (q - r * (r + 1) / 2);
    int i0 = bi * 128, j0 = bj * 128;

    int wave = t >> 6, lane = t & 63;
    int wm = wave >> 1, wn = wave & 1;
    int lr = lane & 15, lg = lane >> 4;

    f32x4 acc[4][4];
#pragma unroll
    for (int m = 0; m < 4; ++m)
#pragma unroll
        for (int n = 0; n < 4; ++n) acc[m][n] = (f32x4){0.f, 0.f, 0.f, 0.f};

    const char* pa = (const char*)a8 + ((size_t)(i0 >> 4) + wm * 4) * 2048 + lg * 128 + lr * 8;
    const char* pbp = (const char*)b8 + ((size_t)(j0 >> 4) + wn * 4) * 2048 + lg * 128 + lr * 8;

#pragma unroll
    for (int ks = 0; ks < 4; ++ks) {
        long af[4], bf[4];
#pragma unroll
        for (int m = 0; m < 4; ++m) af[m] = *(const long*)(pa + m * 2048 + ks * 512);
#pragma unroll
        for (int n = 0; n < 4; ++n) bf[n] = *(const long*)(pbp + n * 2048 + ks * 512);
#pragma unroll
        for (int m = 0; m < 4; ++m)
#pragma unroll
            for (int n = 0; n < 4; ++n)
                acc[m][n] = __builtin_amdgcn_mfma_f32_16x16x32_fp8_fp8(af[m], bf[n], acc[m][n], 0, 0, 0);
    }

    // acc[m][n][q] == -2*dot_fp8(i,j); d2 = acc + sq_i + sq_j.
    // Conservative tile bound: min(acc) + min_tile(sq_i) + min_tile(sq_j).
    float msi = fminf(sq[i0 + lane * 2], sq[i0 + lane * 2 + 1]);
    float msj = fminf(sq[j0 + lane * 2], sq[j0 + lane * 2 + 1]);
#pragma unroll
    for (int off = 32; off >= 1; off >>= 1) {
        msi = fminf(msi, __shfl_xor(msi, off));
        msj = fminf(msj, __shfl_xor(msj, off));
    }
    float mn = acc[0][0][0];
#pragma unroll
    for (int m = 0; m < 4; ++m)
#pragma unroll
        for (int n = 0; n < 4; ++n)
#pragma unroll
            for (int qq = 0; qq < 4; ++qq) mn = fminf(mn, acc[m][n][qq]);

    if (__any(mn + msi + msj < 20.0f)) {
        // Slow path (never taken for this data): exact re-verification from ys.
        float ns = 0.f;
#pragma unroll
        for (int m = 0; m < 4; ++m)
#pragma unroll
            for (int n = 0; n < 4; ++n)
#pragma unroll
                for (int qq = 0; qq < 4; ++qq) {
                    int i = i0 + wm * 64 + m * 16 + lg * 4 + qq;
                    int j = j0 + wn * 64 + n * 16 + lr;
                    float d2a = acc[m][n][qq] + sq[i] + sq[j];
                    if (d2a < 20.0f && i < j && lab[i] != lab[j]) {
                        float d2e = 0.f;
                        for (int d = 0; d < DD; ++d) {
                            float df = ys[(size_t)i * DD + d] - ys[(size_t)j * DD + d];
                            d2e += df * df;
                        }
                        if (d2e < 1.0f) { float e = 1.0f - sqrtf(d2e); ns += e * e; }
                    }
                }
        if (ns != 0.f) atomicAdd(out, ns * SCALE);
    }
}

extern "C" void kernel_launch(void* const* d_in, const int* in_sizes, int n_in,
                              void* d_out, int out_size, void* d_ws, size_t ws_size,
                              hipStream_t stream) {
    const float* ys = (const float*)d_in[0];
    const int* lab = (const int*)d_in[1];
    float* out = (float*)d_out;

    char* w = (char*)d_ws;
    uint32_t* a8    = (uint32_t*)(w);                 // 1 MB (-2y fp8, frag-major)
    uint32_t* b8    = (uint32_t*)(w + 1048576);       // 1 MB (y fp8)
    float* sq       = (float*)(w + 2097152);          // 32 KB
    float* clspart  = (float*)(w + 2129920);          // 4 MB

    prep_kernel<<<NPB, 256, 0, stream>>>(ys, lab, a8, b8, sq, clspart, out);
    loss_kernel<<<TOTBLK, 256, 0, stream>>>(a8, b8, sq, lab, clspart, ys, out);
}